// Round 11
// baseline (475.443 us; speedup 1.0000x reference)
//
#include <hip/hip_runtime.h>
#include <stdint.h>

#define NB 200000
#define BB 4
#define GG 64
#define MAXPOS 128
#define BATCH 256
#define KPT 2                      // anchors per thread in K1
#define CH 512                     // anchors per K1 block (256 thr * KPT)
#define NCH ((NB + CH - 1) / CH)   // 391

// thresholds folded: inter - t*u >= 0  <=>  ((1+t)/t)*inter - (a1+ga) >= 0
#define CP (1.7f / 0.7f)
#define CN (1.3f / 0.3f)

// ---------------- K1: r4 body + relaxed VGPR budget + explicit 8-deep GT loads ----------------
// __launch_bounds__(256,4): grid gives ~6 waves/SIMD, so allow up to 128 VGPRs —
// lets the scheduler keep 8 ds_read_b128 results in flight instead of
// serializing read->lgkmcnt(0)->use at VGPR=28 (r8 probe: 45% real issue occ).
__global__ __launch_bounds__(256, 4) void rpn_flags_kernel(
        const float* __restrict__ anchors, const float* __restrict__ gt,
        uint8_t* __restrict__ flags, uint32_t* __restrict__ chunkCnt,
        uint32_t* __restrict__ done) {
    int b = blockIdx.y;
    int tid = threadIdx.x, lane = tid & 63, wid = tid >> 6;
    if (blockIdx.x == 0 && b == 0 && tid == 0) *done = 0u;  // reset ticket for K2
    __shared__ __align__(16) float4 sG[GG];
    if (tid < GG) sG[tid] = ((const float4*)gt)[b * GG + tid];
    __syncthreads();

    int base = blockIdx.x * CH + tid;          // k=0; k=1 strides by 256
    int i0 = base, i1 = base + 256;
    float4 A0 = (i0 < NB) ? ((const float4*)anchors)[(size_t)b * NB + i0]
                          : make_float4(0.f, 0.f, 0.f, 0.f);
    float4 A1 = (i1 < NB) ? ((const float4*)anchors)[(size_t)b * NB + i1]
                          : make_float4(0.f, 0.f, 0.f, 0.f);
    float na1_0 = -((A0.z - A0.x) * (A0.w - A0.y));
    float na1_1 = -((A1.z - A1.x) * (A1.w - A1.y));
    float mp0 = -1.0f, mn0 = -1.0f, mp1 = -1.0f, mn1 = -1.0f;

#define IOU_BODY(c)                                                         \
    {                                                                       \
        float ga = ((c).z - (c).x) * ((c).w - (c).y);                       \
        float w0 = fmaxf(fminf(A0.z, (c).z) - fmaxf(A0.x, (c).x), 0.0f);    \
        float h0 = fmaxf(fminf(A0.w, (c).w) - fmaxf(A0.y, (c).y), 0.0f);    \
        float in0 = w0 * h0;                                                \
        float ns0 = na1_0 - ga;                                             \
        mp0 = fmaxf(mp0, __builtin_fmaf(CP, in0, ns0));                     \
        mn0 = fmaxf(mn0, __builtin_fmaf(CN, in0, ns0));                     \
        float w1 = fmaxf(fminf(A1.z, (c).z) - fmaxf(A1.x, (c).x), 0.0f);    \
        float h1 = fmaxf(fminf(A1.w, (c).w) - fmaxf(A1.y, (c).y), 0.0f);    \
        float in1 = w1 * h1;                                                \
        float ns1 = na1_1 - ga;                                             \
        mp1 = fmaxf(mp1, __builtin_fmaf(CP, in1, ns1));                     \
        mn1 = fmaxf(mn1, __builtin_fmaf(CN, in1, ns1));                     \
    }

    #pragma unroll
    for (int g0 = 0; g0 < GG; g0 += 8) {
        // 8 named loads first: schedulable as a batch of in-flight ds_read_b128
        float4 c0 = sG[g0 + 0];
        float4 c1 = sG[g0 + 1];
        float4 c2 = sG[g0 + 2];
        float4 c3 = sG[g0 + 3];
        float4 c4 = sG[g0 + 4];
        float4 c5 = sG[g0 + 5];
        float4 c6 = sG[g0 + 6];
        float4 c7 = sG[g0 + 7];
        IOU_BODY(c0); IOU_BODY(c1); IOU_BODY(c2); IOU_BODY(c3);
        IOU_BODY(c4); IOU_BODY(c5); IOU_BODY(c6); IOU_BODY(c7);
    }
#undef IOU_BODY

    bool v0 = i0 < NB, v1 = i1 < NB;
    bool p0 = v0 && (mp0 >= 0.0f), n0 = v0 && (mn0 < 0.0f);
    bool p1 = v1 && (mp1 >= 0.0f), n1 = v1 && (mn1 < 0.0f);
    if (v0) flags[(size_t)b * NB + i0] = (uint8_t)((p0 ? 1 : 0) | (n0 ? 2 : 0));
    if (v1) flags[(size_t)b * NB + i1] = (uint8_t)((p1 ? 1 : 0) | (n1 ? 2 : 0));

    uint32_t pn = (p0 ? 1u : 0u) + (p1 ? 1u : 0u)
                + (n0 ? 0x10000u : 0u) + (n1 ? 0x10000u : 0u);
    for (int off = 32; off > 0; off >>= 1) pn += __shfl_down(pn, off);
    __shared__ uint32_t wSum[4];
    if (lane == 0) wSum[wid] = pn;
    __syncthreads();
    if (tid == 0)
        chunkCnt[b * NCH + blockIdx.x] = wSum[0] + wSum[1] + wSum[2] + wSum[3];
}

// ---------------- K2: scan + ordered selection + loss; last block finalizes ----------------
__global__ __launch_bounds__(1024) void rpn_select_kernel(
        const uint8_t* __restrict__ flags,
        const float* __restrict__ logits, const float* __restrict__ breg,
        const float* __restrict__ anchors, const float* __restrict__ gt,
        const uint32_t* __restrict__ chunkCnt,
        float* __restrict__ partial, uint32_t* __restrict__ done,
        float* __restrict__ out) {
    int b = blockIdx.x;
    const uint8_t* __restrict__ F = flags + (size_t)b * NB;
    __shared__ __align__(16) float4 sG[GG];
    __shared__ int basP[NCH], basN[NCH];
    __shared__ unsigned long long wTot[16];
    __shared__ int sNumPos, sNumNeg;
    __shared__ int selPos[MAXPOS];
    __shared__ int selNeg[BATCH];
    __shared__ float sB, sS;
    __shared__ uint32_t ticket;
    int tid = threadIdx.x, lane = tid & 63, wid = tid >> 6;

    if (tid < GG) sG[tid] = ((const float4*)gt)[b * GG + tid];

    unsigned long long e = 0ULL;
    if (tid < NCH) {
        uint32_t c = chunkCnt[b * NCH + tid];
        e = (unsigned long long)(c & 0xFFFFu) | ((unsigned long long)(c >> 16) << 32);
    }
    unsigned long long inc = e;
    for (int off = 1; off < 64; off <<= 1) {
        unsigned long long v = __shfl_up(inc, off);
        if (lane >= off) inc += v;
    }
    if (lane == 63) wTot[wid] = inc;
    if (tid == 0) { sB = 0.0f; sS = 0.0f; }
    __syncthreads();
    if (wid == 0) {
        unsigned long long w = (lane < 16) ? wTot[lane] : 0ULL;
        unsigned long long winc = w;
        for (int off = 1; off < 16; off <<= 1) {
            unsigned long long v = __shfl_up(winc, off);
            if (lane >= off) winc += v;
        }
        if (lane < 16) wTot[lane] = winc - w;
        if (lane == 15) {
            int tp = (int)(winc & 0xFFFFFFFFULL);
            int tn = (int)(winc >> 32);
            int np_ = min(tp, MAXPOS);
            sNumPos = np_;
            sNumNeg = min(tn, BATCH - np_);
        }
    }
    __syncthreads();
    if (tid < NCH) {
        unsigned long long ex = wTot[wid] + (inc - e);
        basP[tid] = (int)(ex & 0xFFFFFFFFULL);
        basN[tid] = (int)(ex >> 32);
    }
    __syncthreads();
    int numPos = sNumPos, numNeg = sNumNeg;

    for (int c = wid; c < NCH; c += 16) {
        int bp = basP[c], bn = basN[c];
        if (bp >= numPos && bn >= numNeg) break;
        int offP = 0, offN = 0;
        #pragma unroll
        for (int s = 0; s < CH / 64; ++s) {
            int idx = c * CH + s * 64 + lane;
            uint8_t f = (idx < NB) ? F[idx] : (uint8_t)0;
            bool p = (f & 1) != 0, n = (f & 2) != 0;
            unsigned long long mpm = __ballot(p), mnm = __ballot(n);
            unsigned long long lt = (1ULL << lane) - 1ULL;
            int rp = bp + offP + __popcll(mpm & lt);
            int rn = bn + offN + __popcll(mnm & lt);
            if (p && rp < numPos) selPos[rp] = idx;
            if (n && rn < numNeg) selNeg[rn] = idx;
            offP += __popcll(mpm); offN += __popcll(mnm);
        }
    }
    __syncthreads();

    float bce_acc = 0.0f, sl1_acc = 0.0f;
    for (int t = tid; t < numPos; t += 1024) {
        int i = selPos[t];
        float x = logits[(size_t)b * NB + i];
        bce_acc += fmaxf(x, 0.0f) - x + log1pf(expf(-fabsf(x)));
        float4 a = ((const float4*)anchors)[(size_t)b * NB + i];
        float a1 = (a.z - a.x) * (a.w - a.y);
        float ib = -1.0f, ub = 1.0f;
        int bi = 0;
        #pragma unroll 8
        for (int g = 0; g < GG; ++g) {
            float4 c = sG[g];
            float ga = (c.z - c.x) * (c.w - c.y);
            float w = fmaxf(fminf(a.z, c.z) - fmaxf(a.x, c.x), 0.0f);
            float h = fmaxf(fminf(a.w, c.w) - fmaxf(a.y, c.y), 0.0f);
            float inter = w * h;
            float u = (a1 + ga) - inter;
            bool better = inter * ub > ib * u;   // first-max argmax, cross-mult
            ib = better ? inter : ib;
            ub = better ? u : ub;
            bi = better ? g : bi;
        }
        float4 t4 = sG[bi];
        float acx = (a.x + a.z) / 2.0f, acy = (a.y + a.w) / 2.0f;
        float aw = a.z - a.x, ah = a.w - a.y;
        float tcx = (t4.x + t4.z) / 2.0f, tcy = (t4.y + t4.w) / 2.0f;
        float tw = t4.z - t4.x, th = t4.w - t4.y;
        float d0 = (tcx - acx) / aw;
        float d1 = (tcy - acy) / ah;
        float d2 = logf(tw / aw);
        float d3 = logf(th / ah);
        float4 r = ((const float4*)breg)[(size_t)b * NB + i];
        float df;
        df = fabsf(r.x - d0); sl1_acc += (df < 1.0f) ? 0.5f * df * df : df - 0.5f;
        df = fabsf(r.y - d1); sl1_acc += (df < 1.0f) ? 0.5f * df * df : df - 0.5f;
        df = fabsf(r.z - d2); sl1_acc += (df < 1.0f) ? 0.5f * df * df : df - 0.5f;
        df = fabsf(r.w - d3); sl1_acc += (df < 1.0f) ? 0.5f * df * df : df - 0.5f;
    }
    for (int t = tid; t < numNeg; t += 1024) {
        int i = selNeg[t];
        float x = logits[(size_t)b * NB + i];
        bce_acc += fmaxf(x, 0.0f) + log1pf(expf(-fabsf(x)));
    }
    for (int off = 32; off > 0; off >>= 1) {
        bce_acc += __shfl_down(bce_acc, off);
        sl1_acc += __shfl_down(sl1_acc, off);
    }
    if (lane == 0) {
        atomicAdd(&sB, bce_acc);
        atomicAdd(&sS, sl1_acc);
    }
    __syncthreads();
    if (tid == 0) {
        partial[b * 4 + 0] = sB;
        partial[b * 4 + 1] = (float)(numPos + numNeg);
        partial[b * 4 + 2] = sS;
        partial[b * 4 + 3] = (float)numPos;
    }

    // --- last-block finalize (4 blocks -> fences cheap; r7-verified pattern) ---
    __threadfence();                              // release partial[]
    if (tid == 0) ticket = atomicAdd(done, 1u);   // device-scope
    __syncthreads();
    if (ticket != BB - 1) return;
    __threadfence();                              // acquire others' partial[]
    if (tid == 0) {
        float bce = 0.0f, val = 0.0f, sl1 = 0.0f, np = 0.0f;
        #pragma unroll
        for (int w = 0; w < BB; ++w) {
            bce += partial[w * 4 + 0];
            val += partial[w * 4 + 1];
            sl1 += partial[w * 4 + 2];
            np  += partial[w * 4 + 3];
        }
        out[0] = bce / fmaxf(val, 1.0f);
        out[1] = sl1 / fmaxf(np * 4.0f, 1.0f);
    }
}

extern "C" void kernel_launch(void* const* d_in, const int* in_sizes, int n_in,
                              void* d_out, int out_size, void* d_ws, size_t ws_size,
                              hipStream_t stream) {
    const float* cls  = (const float*)d_in[0];  // [B,N,1]
    const float* breg = (const float*)d_in[1];  // [B,N,4]
    const float* anch = (const float*)d_in[2];  // [B,N,4]
    const float* gt   = (const float*)d_in[3];  // [B,G,4]
    float* out = (float*)d_out;

    uint8_t*  flags    = (uint8_t*)d_ws;                            // B*N = 800000
    uint32_t* chunkCnt = (uint32_t*)((uint8_t*)d_ws + 800000);      // B*NCH
    float*    partial  = (float*)(chunkCnt + BB * NCH);             // 16 floats
    uint32_t* done     = (uint32_t*)(partial + 16);

    dim3 g1(NCH, BB);
    rpn_flags_kernel<<<g1, 256, 0, stream>>>(anch, gt, flags, chunkCnt, done);
    rpn_select_kernel<<<BB, 1024, 0, stream>>>(flags, cls, breg, anch, gt,
                                               chunkCnt, partial, done, out);
}

// Round 12
// 28.638 us; speedup vs baseline: 16.6020x; 16.6020x over previous
//
#include <hip/hip_runtime.h>
#include <stdint.h>

#define NB 200000
#define BB 4
#define GG 64
#define MAXPOS 128
#define BATCH 256
#define MPRE 16384                 // prefix length scanned by K1 (exactness checked in K2)
#define CHP 256                    // anchors per K1 block / per selection chunk
#define NCHP (MPRE / CHP)          // 64 chunks per image

// thresholds folded: inter - t*u >= 0  <=>  ((1+t)/t)*inter - (a1+ga) >= 0
#define CP (1.7f / 0.7f)
#define CN (1.3f / 0.3f)

// ---------------- K1: prefix-only per-anchor threshold flags + per-chunk counts ----------------
// Exact r4/r7-proven body (KPT=1), but only over the first MPRE anchors per image.
__global__ __launch_bounds__(256) void rpn_flags_kernel(
        const float* __restrict__ anchors, const float* __restrict__ gt,
        uint8_t* __restrict__ flags, uint32_t* __restrict__ chunkCnt,
        uint32_t* __restrict__ done) {
    int b = blockIdx.y;
    int tid = threadIdx.x, lane = tid & 63, wid = tid >> 6;
    if (blockIdx.x == 0 && b == 0 && tid == 0) *done = 0u;  // reset ticket for K2
    __shared__ __align__(16) float4 sG[GG];
    if (tid < GG) sG[tid] = ((const float4*)gt)[b * GG + tid];
    __syncthreads();

    int i = blockIdx.x * CHP + tid;            // i < MPRE <= NB always
    float4 a = ((const float4*)anchors)[(size_t)b * NB + i];
    float na1 = -((a.z - a.x) * (a.w - a.y));
    float mp = -1.0f, mn = -1.0f;

    #pragma unroll 8
    for (int g = 0; g < GG; ++g) {
        float4 c = sG[g];                       // broadcast ds_read_b128
        float ga = (c.z - c.x) * (c.w - c.y);
        float w = fmaxf(fminf(a.z, c.z) - fmaxf(a.x, c.x), 0.0f);
        float h = fmaxf(fminf(a.w, c.w) - fmaxf(a.y, c.y), 0.0f);
        float inter = w * h;
        float s = na1 - ga;
        mp = fmaxf(mp, __builtin_fmaf(CP, inter, s));
        mn = fmaxf(mn, __builtin_fmaf(CN, inter, s));
    }

    bool p = (mp >= 0.0f);
    bool n = (mn < 0.0f);
    flags[(size_t)b * NB + i] = (uint8_t)((p ? 1 : 0) | (n ? 2 : 0));

    uint32_t pn = (p ? 1u : 0u) + (n ? 0x10000u : 0u);
    for (int off = 32; off > 0; off >>= 1) pn += __shfl_down(pn, off);
    __shared__ uint32_t wSum[4];
    if (lane == 0) wSum[wid] = pn;
    __syncthreads();
    if (tid == 0)
        chunkCnt[b * NCHP + blockIdx.x] = wSum[0] + wSum[1] + wSum[2] + wSum[3];
}

// ---------------- K2: prefix scan + selection + loss; exactness check + fallback; finalize ----------------
__global__ __launch_bounds__(1024) void rpn_select_kernel(
        const uint8_t* __restrict__ flags,
        const float* __restrict__ logits, const float* __restrict__ breg,
        const float* __restrict__ anchors, const float* __restrict__ gt,
        const uint32_t* __restrict__ chunkCnt,
        float* __restrict__ partial, uint32_t* __restrict__ done,
        float* __restrict__ out) {
    int b = blockIdx.x;
    const uint8_t* __restrict__ F = flags + (size_t)b * NB;
    __shared__ __align__(16) float4 sG[GG];
    __shared__ int basP[NCHP], basN[NCHP];
    __shared__ int sTotP, sTotN, sNumPos, sNumNeg;
    __shared__ int selPos[MAXPOS];
    __shared__ int selNeg[BATCH];
    __shared__ float sB, sS;
    __shared__ uint32_t ticket;
    int tid = threadIdx.x, lane = tid & 63, wid = tid >> 6;

    if (tid < GG) sG[tid] = ((const float4*)gt)[b * GG + tid];
    if (tid == 0) { sB = 0.0f; sS = 0.0f; }

    // --- wave0: exclusive scan of the 64 packed (pos, neg) prefix-chunk counts ---
    if (wid == 0) {
        unsigned long long e = 0ULL;
        if (lane < NCHP) {
            uint32_t c = chunkCnt[b * NCHP + lane];
            e = (unsigned long long)(c & 0xFFFFu) | ((unsigned long long)(c >> 16) << 32);
        }
        unsigned long long inc = e;
        for (int off = 1; off < 64; off <<= 1) {
            unsigned long long v = __shfl_up(inc, off);
            if (lane >= off) inc += v;
        }
        if (lane < NCHP) {
            unsigned long long ex = inc - e;
            basP[lane] = (int)(ex & 0xFFFFFFFFULL);
            basN[lane] = (int)(ex >> 32);
        }
        unsigned long long tot = __shfl(inc, 63);
        if (lane == 0) {
            sTotP = (int)(tot & 0xFFFFFFFFULL);
            sTotN = (int)(tot >> 32);
        }
    }
    __syncthreads();

    // exactness check: prefix has enough of both -> quotas and all selected
    // indices provably lie in the prefix (first-k-by-index semantics).
    bool fast = (sTotP >= MAXPOS) && (sTotN >= BATCH - MAXPOS);
    int numPos, numNeg;

    if (fast) {
        numPos = MAXPOS; numNeg = BATCH - MAXPOS;
        // parallel ordered selection: wave w handles chunks w, w+16, ...
        for (int c = wid; c < NCHP; c += 16) {
            int bp = basP[c], bn = basN[c];
            if (bp >= numPos && bn >= numNeg) break;   // bases monotone, wave-uniform
            int offP = 0, offN = 0;
            #pragma unroll
            for (int s = 0; s < CHP / 64; ++s) {
                int idx = c * CHP + s * 64 + lane;     // idx < MPRE always
                uint8_t f = F[idx];
                bool p = (f & 1) != 0, n = (f & 2) != 0;
                unsigned long long mpm = __ballot(p), mnm = __ballot(n);
                unsigned long long lt = (1ULL << lane) - 1ULL;
                int rp = bp + offP + __popcll(mpm & lt);
                int rn = bn + offN + __popcll(mnm & lt);
                if (p && rp < numPos) selPos[rp] = idx;
                if (n && rn < numNeg) selNeg[rn] = idx;
                offP += __popcll(mpm); offN += __popcll(mnm);
            }
        }
    } else {
        // exact fallback (never taken for the benchmark data): wave0 sequential
        // scan over ALL anchors, computing flags beyond the prefix on the fly.
        if (wid == 0) {
            int totP = 0, totN = 0;
            for (int g0 = 0; g0 < NB; g0 += 64) {
                int idx = g0 + lane;
                bool p = false, n = false;
                if (idx < NB) {
                    if (idx < MPRE) {
                        uint8_t f = F[idx];
                        p = (f & 1) != 0; n = (f & 2) != 0;
                    } else {
                        float4 a = ((const float4*)anchors)[(size_t)b * NB + idx];
                        float na1 = -((a.z - a.x) * (a.w - a.y));
                        float mp = -1.0f, mn = -1.0f;
                        for (int g = 0; g < GG; ++g) {
                            float4 c = sG[g];
                            float ga = (c.z - c.x) * (c.w - c.y);
                            float w = fmaxf(fminf(a.z, c.z) - fmaxf(a.x, c.x), 0.0f);
                            float h = fmaxf(fminf(a.w, c.w) - fmaxf(a.y, c.y), 0.0f);
                            float inter = w * h;
                            float s = na1 - ga;
                            mp = fmaxf(mp, __builtin_fmaf(CP, inter, s));
                            mn = fmaxf(mn, __builtin_fmaf(CN, inter, s));
                        }
                        p = (mp >= 0.0f); n = (mn < 0.0f);
                    }
                }
                unsigned long long mpm = __ballot(p), mnm = __ballot(n);
                unsigned long long lt = (1ULL << lane) - 1ULL;
                int rp = totP + __popcll(mpm & lt);
                int rn = totN + __popcll(mnm & lt);
                if (p && rp < MAXPOS) selPos[rp] = idx;
                if (n && rn < BATCH) selNeg[rn] = idx;
                totP += __popcll(mpm); totN += __popcll(mnm);
                if (totP >= MAXPOS && totN >= BATCH) break;  // quotas resolvable
            }
            if (lane == 0) {
                int np = min(totP, MAXPOS);
                sNumPos = np;
                sNumNeg = min(totN, BATCH - np);
            }
        }
    }
    __syncthreads();
    if (!fast) { numPos = sNumPos; numNeg = sNumNeg; }

    // --- losses over selected samples ---
    float bce_acc = 0.0f, sl1_acc = 0.0f;
    for (int t = tid; t < numPos; t += 1024) {
        int i = selPos[t];
        float x = logits[(size_t)b * NB + i];
        bce_acc += fmaxf(x, 0.0f) - x + log1pf(expf(-fabsf(x)));
        float4 a = ((const float4*)anchors)[(size_t)b * NB + i];
        float a1 = (a.z - a.x) * (a.w - a.y);
        // argmax over gts (cross-mult, first-max) for this positive
        float ib = -1.0f, ub = 1.0f;
        int bi = 0;
        #pragma unroll 8
        for (int g = 0; g < GG; ++g) {
            float4 c = sG[g];
            float ga = (c.z - c.x) * (c.w - c.y);
            float w = fmaxf(fminf(a.z, c.z) - fmaxf(a.x, c.x), 0.0f);
            float h = fmaxf(fminf(a.w, c.w) - fmaxf(a.y, c.y), 0.0f);
            float inter = w * h;
            float u = (a1 + ga) - inter;
            bool better = inter * ub > ib * u;
            ib = better ? inter : ib;
            ub = better ? u : ub;
            bi = better ? g : bi;
        }
        float4 t4 = sG[bi];
        float acx = (a.x + a.z) / 2.0f, acy = (a.y + a.w) / 2.0f;
        float aw = a.z - a.x, ah = a.w - a.y;
        float tcx = (t4.x + t4.z) / 2.0f, tcy = (t4.y + t4.w) / 2.0f;
        float tw = t4.z - t4.x, th = t4.w - t4.y;
        float d0 = (tcx - acx) / aw;
        float d1 = (tcy - acy) / ah;
        float d2 = logf(tw / aw);
        float d3 = logf(th / ah);
        float4 r = ((const float4*)breg)[(size_t)b * NB + i];
        float df;
        df = fabsf(r.x - d0); sl1_acc += (df < 1.0f) ? 0.5f * df * df : df - 0.5f;
        df = fabsf(r.y - d1); sl1_acc += (df < 1.0f) ? 0.5f * df * df : df - 0.5f;
        df = fabsf(r.z - d2); sl1_acc += (df < 1.0f) ? 0.5f * df * df : df - 0.5f;
        df = fabsf(r.w - d3); sl1_acc += (df < 1.0f) ? 0.5f * df * df : df - 0.5f;
    }
    for (int t = tid; t < numNeg; t += 1024) {
        int i = selNeg[t];
        float x = logits[(size_t)b * NB + i];
        bce_acc += fmaxf(x, 0.0f) + log1pf(expf(-fabsf(x)));
    }
    for (int off = 32; off > 0; off >>= 1) {
        bce_acc += __shfl_down(bce_acc, off);
        sl1_acc += __shfl_down(sl1_acc, off);
    }
    if (lane == 0) {
        atomicAdd(&sB, bce_acc);
        atomicAdd(&sS, sl1_acc);
    }
    __syncthreads();
    if (tid == 0) {
        partial[b * 4 + 0] = sB;
        partial[b * 4 + 1] = (float)(numPos + numNeg);
        partial[b * 4 + 2] = sS;
        partial[b * 4 + 3] = (float)numPos;
    }

    // --- last-block finalize (4 blocks; r7-verified ticket pattern) ---
    __threadfence();                              // release partial[]
    if (tid == 0) ticket = atomicAdd(done, 1u);   // device-scope
    __syncthreads();
    if (ticket != BB - 1) return;
    __threadfence();                              // acquire others' partial[]
    if (tid == 0) {
        float bce = 0.0f, val = 0.0f, sl1 = 0.0f, np = 0.0f;
        #pragma unroll
        for (int w = 0; w < BB; ++w) {
            bce += partial[w * 4 + 0];
            val += partial[w * 4 + 1];
            sl1 += partial[w * 4 + 2];
            np  += partial[w * 4 + 3];
        }
        out[0] = bce / fmaxf(val, 1.0f);
        out[1] = sl1 / fmaxf(np * 4.0f, 1.0f);
    }
}

extern "C" void kernel_launch(void* const* d_in, const int* in_sizes, int n_in,
                              void* d_out, int out_size, void* d_ws, size_t ws_size,
                              hipStream_t stream) {
    const float* cls  = (const float*)d_in[0];  // [B,N,1]
    const float* breg = (const float*)d_in[1];  // [B,N,4]
    const float* anch = (const float*)d_in[2];  // [B,N,4]
    const float* gt   = (const float*)d_in[3];  // [B,G,4]
    float* out = (float*)d_out;

    uint8_t*  flags    = (uint8_t*)d_ws;                            // B*N (prefix used)
    uint32_t* chunkCnt = (uint32_t*)((uint8_t*)d_ws + 800000);      // B*NCHP
    float*    partial  = (float*)(chunkCnt + BB * NCHP);            // 16 floats
    uint32_t* done     = (uint32_t*)(partial + 16);

    dim3 g1(NCHP, BB);
    rpn_flags_kernel<<<g1, 256, 0, stream>>>(anch, gt, flags, chunkCnt, done);
    rpn_select_kernel<<<BB, 1024, 0, stream>>>(flags, cls, breg, anch, gt,
                                               chunkCnt, partial, done, out);
}